// Round 6
// baseline (206.022 us; speedup 1.0000x reference)
//
#include <hip/hip_runtime.h>
#include <cmath>

#define IH 128
#define IW 128
#define NB 8

typedef __attribute__((ext_vector_type(8))) short bf16x8;
typedef __attribute__((ext_vector_type(4))) float f32x4;
typedef __attribute__((ext_vector_type(2))) float f32x2;

union U4B8 { uint4 u; bf16x8 h; };

// ws layout (float slots) — offm slot retained but unused after fusion:
//   offm  : [NB][27][IH][IW] f32      = 3538944
//   xT    : [NB][IH][IW][64] bf16     = 4194304 float slots (8388608 u16)
//   wt_dc : [9][64][64] bf16 (k,o,c)  = 18432 float slots
//   wt_om : [9][32][64] bf16 (k,o,c)  = 9216  float slots
#define OFFM_OFF 0
#define XT_OFF   3538944
#define WTDC_OFF (3538944 + 4194304)
#define WTOM_OFF (3538944 + 4194304 + 18432)

// fp32 -> bf16 bits, round-to-nearest-even
__device__ __forceinline__ unsigned short f32_to_bf16(float f) {
    unsigned int u = __float_as_uint(f);
    u += 0x7fffu + ((u >> 16) & 1u);
    return (unsigned short)(u >> 16);
}

// ---------------------------------------------------------------------------
// Kernel 0: weights -> bf16, layout [k][o][c]
// ---------------------------------------------------------------------------
__global__ void transpose_weights(const float* __restrict__ w_dc,
                                  const float* __restrict__ w_om,
                                  unsigned short* __restrict__ wt_dc16,
                                  unsigned short* __restrict__ wt_om16) {
    int idx = blockIdx.x * blockDim.x + threadIdx.x;
    if (idx < 9 * 64 * 64) {
        int k = idx >> 12;
        int o = (idx >> 6) & 63;
        int c = idx & 63;
        wt_dc16[idx] = f32_to_bf16(w_dc[(o * 64 + c) * 9 + k]);
    }
    if (idx < 9 * 32 * 64) {
        int k = idx >> 11;
        int o = (idx >> 6) & 31;
        int c = idx & 63;
        wt_om16[idx] = (o < 27) ? f32_to_bf16(w_om[(o * 64 + c) * 9 + k])
                                : (unsigned short)0;
    }
}

// ---------------------------------------------------------------------------
// Kernel 0b: x NCHW fp32 -> NHWC bf16 (xT[b][y][x][c]) — VECTORIZED.
// Old version: scalar 4B loads + 4B ushort2 stores (Common-mistake #2);
// budget arithmetic says it cost ~70 µs for 50 MB. New: block = one (b,h)
// row; float4 coalesced reads -> LDS [c][w] tile -> cvt_pk_bf16 -> uint4
// (16B) coalesced stores. 1 KB per wave-instr both directions.
// ---------------------------------------------------------------------------
__global__ __launch_bounds__(256) void transpose_x(
        const float* __restrict__ x, unsigned short* __restrict__ xT) {
    __shared__ __align__(16) float t[64][132];   // 132: 16B-aligned rows, +pad
    const int tid = threadIdx.x;
    const int b = blockIdx.x >> 7;
    const int h = blockIdx.x & 127;

#pragma unroll
    for (int j = 0; j < 8; ++j) {
        const int i = (j << 8) + tid;       // 0..2047
        const int c = i >> 5;               // 0..63
        const int w4 = i & 31;              // float4 index within row
        const float4 v = *(const float4*)&x[(((size_t)(b * 64 + c)) << 14) + (h << 7) + (w4 << 2)];
        *(float4*)&t[c][w4 << 2] = v;
    }
    __syncthreads();

#pragma unroll
    for (int j = 0; j < 4; ++j) {
        const int u = (j << 8) + tid;       // 0..1023
        const int px = u & 127;
        const int cg = u >> 7;              // channel-group of 8
        unsigned int pk[4];
#pragma unroll
        for (int e = 0; e < 4; ++e) {
            const float lo = t[(cg << 3) + 2 * e][px];
            const float hi = t[(cg << 3) + 2 * e + 1][px];
            asm("v_cvt_pk_bf16_f32 %0, %1, %2" : "=v"(pk[e]) : "v"(lo), "v"(hi));
        }
        *(uint4*)(xT + (((size_t)b << 20) + ((size_t)((h << 7) + px) << 6) + (cg << 3))) =
            make_uint4(pk[0], pk[1], pk[2], pk[3]);
    }
}

// ---------------------------------------------------------------------------
// gather issue phase (deform): compute corner weights (msk premultiplied) and
// ISSUE the 8 corner loads into registers. Consumed one tap later.
// offs is an LDS pointer, stride 65 floats per channel.
// ---------------------------------------------------------------------------
__device__ __forceinline__ void issue_gather(
        const unsigned short* __restrict__ xb, const float* offs,
        int k, int lpx, int h, int w0, int quad, uint4* g, float* cw) {
    const float offy = offs[(k << 1) * 65 + lpx];
    const float offx = offs[((k << 1) + 1) * 65 + lpx];
    const float msk  = offs[(18 + k) * 65 + lpx];
    const int kh = k / 3;
    const int kw = k - kh * 3;
    const float py  = (float)(h + kh - 1) + offy;
    const float pxf = (float)(w0 + lpx + kw - 1) + offx;
    const float y0f = floorf(py);
    const float x0f = floorf(pxf);
    const float fy = py - y0f;
    const float fx = pxf - x0f;
    const float wy0 = 1.0f - fy, wx0 = 1.0f - fx;
    const float vy0 = (y0f >= 0.0f && y0f <= 127.0f) ? 1.0f : 0.0f;
    const float vy1 = (y0f >= -1.0f && y0f <= 126.0f) ? 1.0f : 0.0f;
    const float vx0 = (x0f >= 0.0f && x0f <= 127.0f) ? 1.0f : 0.0f;
    const float vx1 = (x0f >= -1.0f && x0f <= 126.0f) ? 1.0f : 0.0f;
    cw[0] = wy0 * wx0 * vy0 * vx0 * msk;
    cw[1] = wy0 * fx  * vy0 * vx1 * msk;
    cw[2] = fy  * wx0 * vy1 * vx0 * msk;
    cw[3] = fy  * fx  * vy1 * vx1 * msk;
    const int y0i = min(max((int)y0f, 0), 127);
    const int y1i = min(max((int)y0f + 1, 0), 127);
    const int x0i = min(max((int)x0f, 0), 127);
    const int x1i = min(max((int)x0f + 1, 0), 127);
    const int cofs = quad << 3;
    const unsigned short* p00 = xb + ((((size_t)((y0i << 7) + x0i)) << 6) + cofs);
    const unsigned short* p01 = xb + ((((size_t)((y0i << 7) + x1i)) << 6) + cofs);
    const unsigned short* p10 = xb + ((((size_t)((y1i << 7) + x0i)) << 6) + cofs);
    const unsigned short* p11 = xb + ((((size_t)((y1i << 7) + x1i)) << 6) + cofs);
    g[0] = *(const uint4*)p00;  g[1] = *(const uint4*)(p00 + 32);
    g[2] = *(const uint4*)p01;  g[3] = *(const uint4*)(p01 + 32);
    g[4] = *(const uint4*)p10;  g[5] = *(const uint4*)(p10 + 32);
    g[6] = *(const uint4*)p11;  g[7] = *(const uint4*)(p11 + 32);
}

// ---------------------------------------------------------------------------
// consume phase: combine 8 corner vectors with 4 (msk-premul) weights via
// packed-f32 FMA, pack to bf16 A-fragments via hw cvt_pk.
// ---------------------------------------------------------------------------
__device__ __forceinline__ void pack_frags(const uint4* g, const float* cw,
                                           U4B8& a0, U4B8& a1) {
    f32x2 v2[8];
#pragma unroll
    for (int i = 0; i < 8; ++i) v2[i] = (f32x2){0.f, 0.f};
#pragma unroll
    for (int c = 0; c < 4; ++c) {
        f32x2 w2;
        w2.x = cw[c];
        w2.y = cw[c];
        const uint4 ga = g[2 * c];
        const uint4 gb = g[2 * c + 1];
        const unsigned int u[8] = {ga.x, ga.y, ga.z, ga.w, gb.x, gb.y, gb.z, gb.w};
#pragma unroll
        for (int i = 0; i < 8; ++i) {
            f32x2 x2;
            x2.x = __uint_as_float(u[i] << 16);
            x2.y = __uint_as_float(u[i] & 0xffff0000u);
            asm("v_pk_fma_f32 %0, %1, %2, %0" : "+v"(v2[i]) : "v"(x2), "v"(w2));
        }
    }
    unsigned int pk[8];
#pragma unroll
    for (int i = 0; i < 8; ++i)
        asm("v_cvt_pk_bf16_f32 %0, %1, %2"
            : "=v"(pk[i]) : "v"(v2[i].x), "v"(v2[i].y));
    a0.u = make_uint4(pk[0], pk[1], pk[2], pk[3]);
    a1.u = make_uint4(pk[4], pk[5], pk[6], pk[7]);
}

// LDS union: phase 1 needs the 28.5 KB input window; phase 2 needs
// offs (7 KB) + weight dbuf (18.4 KB). They never coexist -> union, 28.5 KB.
struct P2Mem {
    float offs[27 * 65];                   // [ch][px] pad-65
    unsigned short wks[2][64 * 72];        // [buf][o][72]
};
union SMem {
    unsigned short win[198 * 72];          // [3*66][72] phase-1 window
    P2Mem p2;
};

// ---------------------------------------------------------------------------
// FUSED kernel: offset/mask conv (phase 1) + deformable conv (phase 2).
// Phase 1 (R5 lesson): A-frags MUST come from the staged LDS window (9x
// reuse) — per-tap global A-loads were a 2.4x phase-1 regression. B-frags
// register-pipelined from global (4 loads in flight, no vmcnt trap).
// Result written to LDS offs (no offm global round-trip).
// Phase 2 = R4 deform: gather reg-pipeline + LDS weight dbuf + lgkm-only
// barrier (gather loads stay in flight across taps).
// ---------------------------------------------------------------------------
__global__ __launch_bounds__(256) void om_deform_fused(
        const unsigned short* __restrict__ xT,
        const float* __restrict__ b_om,
        const unsigned short* __restrict__ wt_om16,  // [9][32][64]
        const float* __restrict__ b_dc,
        const unsigned short* __restrict__ wt_dc16,  // [9][64][64]
        float* __restrict__ out) {
    __shared__ __align__(16) SMem sm;

    const int tid = threadIdx.x;
    const int bid = blockIdx.x;
    const int swz = ((bid & 7) << 8) + (bid >> 3);   // XCD-contiguous
    const int b = swz >> 8;
    const int rem = swz & 255;
    const int h = rem >> 1;
    const int w0 = (rem & 1) << 6;
    const int wid = tid >> 6;
    const int lane = tid & 63;
    const int ln15 = lane & 15;
    const int quad = lane >> 4;
    const int lpx = (wid << 4) + ln15;   // local pixel this lane owns

    const unsigned short* xb = xT + ((size_t)b << 20);

    // ======================= phase 1: offset/mask conv ======================
    // stage 3-row, 66-px window of xT (zero-padded at borders)
    for (int idx = tid; idx < 1584; idx += 256) {
        const int pos = idx >> 3;
        const int part = idx & 7;
        const int r = pos / 66;
        const int xx = pos - r * 66;
        const int y = h + r - 1;
        const int xg = w0 + xx - 1;
        uint4 v = make_uint4(0u, 0u, 0u, 0u);
        if (y >= 0 && y < IH && xg >= 0 && xg < IW)
            v = *(const uint4*)(xT + (((size_t)b << 20) + (((y << 7) + xg) << 6) + (part << 3)));
        *(uint4*)&sm.win[pos * 72 + part * 8] = v;
    }
    __syncthreads();

    f32x4 oacc[2] = {{0.f, 0.f, 0.f, 0.f}, {0.f, 0.f, 0.f, 0.f}};
    uint4 pb[2][4];

#define ISSUE_B(K, S)                                                         \
    {                                                                         \
        const unsigned short* wg_ = wt_om16 + ((K) << 11) + (quad << 3);      \
        const unsigned short* q0_ = wg_ + (ln15 << 6);                        \
        const unsigned short* q1_ = wg_ + ((16 + ln15) << 6);                 \
        pb[S][0] = *(const uint4*)q0_;                                        \
        pb[S][1] = *(const uint4*)(q0_ + 32);                                 \
        pb[S][2] = *(const uint4*)q1_;                                        \
        pb[S][3] = *(const uint4*)(q1_ + 32);                                 \
    }

    ISSUE_B(0, 0)
#pragma unroll
    for (int k = 0; k < 9; ++k) {
        const int cur = k & 1;
        const int nxt = cur ^ 1;
        if (k < 8) ISSUE_B(k + 1, nxt)       // pipeline B one tap ahead
        const int kh = k / 3;
        const int kw = k - kh * 3;
        const int posb = kh * 66 + lpx + kw;
        U4B8 a0, a1, b00, b01, b10, b11;
        a0.u = *(const uint4*)&sm.win[posb * 72 + (quad << 3)];        // ch 0-31
        a1.u = *(const uint4*)&sm.win[posb * 72 + 32 + (quad << 3)];   // ch 32-63
        b00.u = pb[cur][0];
        b01.u = pb[cur][1];
        b10.u = pb[cur][2];
        b11.u = pb[cur][3];
        oacc[0] = __builtin_amdgcn_mfma_f32_16x16x32_bf16(a0.h, b00.h, oacc[0], 0, 0, 0);
        oacc[0] = __builtin_amdgcn_mfma_f32_16x16x32_bf16(a1.h, b01.h, oacc[0], 0, 0, 0);
        oacc[1] = __builtin_amdgcn_mfma_f32_16x16x32_bf16(a0.h, b10.h, oacc[1], 0, 0, 0);
        oacc[1] = __builtin_amdgcn_mfma_f32_16x16x32_bf16(a1.h, b11.h, oacc[1], 0, 0, 0);
    }
#undef ISSUE_B

    // all waves done reading win before we overwrite it with offs/wks
    __syncthreads();

    // stage wt_dc k=0 into wks[0] (2 x uint4 per thread)
    const int so0 = tid >> 3, sp = tid & 7;
    const int so1 = so0 + 32;
    {
        const uint4 wv0 = *(const uint4*)(wt_dc16 + (so0 << 6) + (sp << 3));
        const uint4 wv1 = *(const uint4*)(wt_dc16 + (so1 << 6) + (sp << 3));
        *(uint4*)&sm.p2.wks[0][so0 * 72 + sp * 8] = wv0;
        *(uint4*)&sm.p2.wks[0][so1 * 72 + sp * 8] = wv1;
    }

    // epilogue phase 1: bias (+2*sigmoid for mask ch) -> offs[ch][px] in LDS
    // C/D layout: col(o)=lane&15, row(px)=quad*4+reg
    const int px0 = (wid << 4) + (quad << 2);
#pragma unroll
    for (int ot = 0; ot < 2; ++ot) {
        const int o = (ot << 4) + ln15;
        if (o < 27) {
            const float bias = b_om[o];
            float r[4];
            r[0] = oacc[ot][0] + bias;
            r[1] = oacc[ot][1] + bias;
            r[2] = oacc[ot][2] + bias;
            r[3] = oacc[ot][3] + bias;
            if (o >= 18) {
#pragma unroll
                for (int j = 0; j < 4; ++j)
                    r[j] = 2.0f / (1.0f + __expf(-r[j]));
            }
#pragma unroll
            for (int j = 0; j < 4; ++j)
                sm.p2.offs[o * 65 + px0 + j] = r[j];
        }
    }
    __syncthreads();

    // ========================= phase 2: deform conv =========================
    f32x4 acc[4];
#pragma unroll
    for (int i = 0; i < 4; ++i) acc[i] = (f32x4){0.f, 0.f, 0.f, 0.f};

    uint4 g[2][8];
    float cw[2][4];
    issue_gather(xb, sm.p2.offs, 0, lpx, h, w0, quad, g[0], cw[0]);

#pragma unroll
    for (int k = 0; k < 9; ++k) {
        const int cur = k & 1;
        const int nxt = cur ^ 1;
        if (k < 8) {
            // 1) weight loads for k+1 (oldest in this iter's vmem FIFO)
            const uint4 wv0 = *(const uint4*)(wt_dc16 + ((k + 1) << 12) + (so0 << 6) + (sp << 3));
            const uint4 wv1 = *(const uint4*)(wt_dc16 + ((k + 1) << 12) + (so1 << 6) + (sp << 3));
            // 2) issue next-tap gather loads (newest — stay in flight)
            issue_gather(xb, sm.p2.offs, k + 1, lpx, h, w0, quad, g[nxt], cw[nxt]);
            // 3) ds_write W: waits vmcnt(8) -> drains W + gather(k) only
            *(uint4*)&sm.p2.wks[nxt][so0 * 72 + sp * 8] = wv0;
            *(uint4*)&sm.p2.wks[nxt][so1 * 72 + sp * 8] = wv1;
        }
        // 4) pack tap k from last iteration's registers
        U4B8 a0, a1;
        pack_frags(g[cur], cw[cur], a0, a1);
        // 5) MFMA from LDS weight broadcast
        const unsigned short* wb = sm.p2.wks[cur];
#pragma unroll
        for (int ot = 0; ot < 4; ++ot) {
            U4B8 b0, b1;
            const unsigned short* base = &wb[((ot << 4) + ln15) * 72 + (quad << 3)];
            b0.u = *(const uint4*)base;
            b1.u = *(const uint4*)(base + 32);
            acc[ot] = __builtin_amdgcn_mfma_f32_16x16x32_bf16(a0.h, b0.h, acc[ot], 0, 0, 0);
            acc[ot] = __builtin_amdgcn_mfma_f32_16x16x32_bf16(a1.h, b1.h, acc[ot], 0, 0, 0);
        }
        // 6) dbuf barrier: LDS-only wait — gather(k+1) loads stay in flight
        if (k < 8) {
            asm volatile("s_waitcnt lgkmcnt(0)" ::: "memory");
            __builtin_amdgcn_s_barrier();
            __builtin_amdgcn_sched_barrier(0);
        }
    }

    // epilogue: col(o)=lane&15, row(px)=quad*4+reg
#pragma unroll
    for (int ot = 0; ot < 4; ++ot) {
        const int o = (ot << 4) + ln15;
        const float bias = b_dc[o];
        float4 r;
        r.x = acc[ot][0] + bias;
        r.y = acc[ot][1] + bias;
        r.z = acc[ot][2] + bias;
        r.w = acc[ot][3] + bias;
        *(float4*)&out[(((size_t)(b * 64 + o)) << 14) + (h << 7) + w0 + (wid << 4) + (quad << 2)] = r;
    }
}

extern "C" void kernel_launch(void* const* d_in, const int* in_sizes, int n_in,
                              void* d_out, int out_size, void* d_ws, size_t ws_size,
                              hipStream_t stream) {
    const float* x    = (const float*)d_in[0];
    const float* w_om = (const float*)d_in[1];
    const float* b_om = (const float*)d_in[2];
    const float* w_dc = (const float*)d_in[3];
    const float* b_dc = (const float*)d_in[4];
    float* out = (float*)d_out;
    float* ws  = (float*)d_ws;

    unsigned short* xT      = (unsigned short*)(ws + XT_OFF);
    unsigned short* wt_dc16 = (unsigned short*)(ws + WTDC_OFF);
    unsigned short* wt_om16 = (unsigned short*)(ws + WTOM_OFF);

    // 64-px blocks: NB*IH*(IW/64) = 2048 blocks
    const int n_blocks = NB * IH * (IW / 64);

    transpose_weights<<<144, 256, 0, stream>>>(w_dc, w_om, wt_dc16, wt_om16);
    transpose_x<<<NB * IH, 256, 0, stream>>>(x, xT);
    om_deform_fused<<<n_blocks, 256, 0, stream>>>(xT, b_om, wt_om16, b_dc, wt_dc16, out);
}

// Round 7
// 181.009 us; speedup vs baseline: 1.1382x; 1.1382x over previous
//
#include <hip/hip_runtime.h>
#include <cmath>

#define IH 128
#define IW 128
#define NB 8
#define OFFS_STRIDE 129

typedef __attribute__((ext_vector_type(8))) short bf16x8;
typedef __attribute__((ext_vector_type(4))) float f32x4;
typedef __attribute__((ext_vector_type(2))) float f32x2;

union U4B8 { uint4 u; bf16x8 h; };

// ws layout (float slots):
//   offm  : [NB][27][IH][IW] f32      = 3538944
//   xT    : [NB][IH][IW][64] bf16     = 4194304 float slots (8388608 u16)
//   wt_dc : [9][64][64] bf16 (k,o,c)  = 18432 float slots
//   wt_om : [9][32][64] bf16 (k,o,c)  = 9216  float slots
#define OFFM_OFF 0
#define XT_OFF   3538944
#define WTDC_OFF (3538944 + 4194304)
#define WTOM_OFF (3538944 + 4194304 + 18432)

// fp32 -> bf16 bits, round-to-nearest-even
__device__ __forceinline__ unsigned short f32_to_bf16(float f) {
    unsigned int u = __float_as_uint(f);
    u += 0x7fffu + ((u >> 16) & 1u);
    return (unsigned short)(u >> 16);
}

// ---------------------------------------------------------------------------
// Kernel 0: weights -> bf16, layout [k][o][c]
// ---------------------------------------------------------------------------
__global__ void transpose_weights(const float* __restrict__ w_dc,
                                  const float* __restrict__ w_om,
                                  unsigned short* __restrict__ wt_dc16,
                                  unsigned short* __restrict__ wt_om16) {
    int idx = blockIdx.x * blockDim.x + threadIdx.x;
    if (idx < 9 * 64 * 64) {
        int k = idx >> 12;
        int o = (idx >> 6) & 63;
        int c = idx & 63;
        wt_dc16[idx] = f32_to_bf16(w_dc[(o * 64 + c) * 9 + k]);
    }
    if (idx < 9 * 32 * 64) {
        int k = idx >> 11;
        int o = (idx >> 6) & 31;
        int c = idx & 63;
        wt_om16[idx] = (o < 27) ? f32_to_bf16(w_om[(o * 64 + c) * 9 + k])
                                : (unsigned short)0;
    }
}

// ---------------------------------------------------------------------------
// Kernel 0b: x NCHW fp32 -> NHWC bf16 (xT[b][y][x][c]) — vectorized (R6).
// float4 coalesced reads -> LDS [c][w] tile -> cvt_pk_bf16 -> uint4 stores.
// ---------------------------------------------------------------------------
__global__ __launch_bounds__(256) void transpose_x(
        const float* __restrict__ x, unsigned short* __restrict__ xT) {
    __shared__ __align__(16) float t[64][132];   // 132: 16B-aligned rows, +pad
    const int tid = threadIdx.x;
    const int b = blockIdx.x >> 7;
    const int h = blockIdx.x & 127;

#pragma unroll
    for (int j = 0; j < 8; ++j) {
        const int i = (j << 8) + tid;       // 0..2047
        const int c = i >> 5;               // 0..63
        const int w4 = i & 31;              // float4 index within row
        const float4 v = *(const float4*)&x[(((size_t)(b * 64 + c)) << 14) + (h << 7) + (w4 << 2)];
        *(float4*)&t[c][w4 << 2] = v;
    }
    __syncthreads();

#pragma unroll
    for (int j = 0; j < 4; ++j) {
        const int u = (j << 8) + tid;       // 0..1023
        const int px = u & 127;
        const int cg = u >> 7;              // channel-group of 8
        unsigned int pk[4];
#pragma unroll
        for (int e = 0; e < 4; ++e) {
            const float lo = t[(cg << 3) + 2 * e][px];
            const float hi = t[(cg << 3) + 2 * e + 1][px];
            asm("v_cvt_pk_bf16_f32 %0, %1, %2" : "=v"(pk[e]) : "v"(lo), "v"(hi));
        }
        *(uint4*)(xT + (((size_t)b << 20) + ((size_t)((h << 7) + px) << 6) + (cg << 3))) =
            make_uint4(pk[0], pk[1], pk[2], pk[3]);
    }
}

// ---------------------------------------------------------------------------
// Kernel 1: conv3x3 -> offset/mask (R3 version verbatim — proven ~19 µs).
// Block = 64px x 32o, 4 waves. Window staged once; weights double-buffered
// in LDS, ONE barrier per k. XCD swizzle: each XCD owns one image.
// ---------------------------------------------------------------------------
__global__ __launch_bounds__(256) void conv_om_mfma(
        const unsigned short* __restrict__ xT,
        const float* __restrict__ b_om,
        const unsigned short* __restrict__ wt_om16,  // [9][32][64]
        float* __restrict__ offm) {
    __shared__ __align__(16) unsigned short win[198 * 72];   // [3*66][72]
    __shared__ __align__(16) unsigned short wks[2][32 * 72]; // [buf][o][72]

    const int tid = threadIdx.x;
    const int bid = blockIdx.x;
    const int swz = ((bid & 7) << 8) + (bid >> 3);   // XCD-contiguous
    const int b = swz >> 8;
    const int rem = swz & 255;
    const int h = rem >> 1;
    const int w0 = (rem & 1) << 6;
    const int wid = tid >> 6;
    const int lane = tid & 63;
    const int ln15 = lane & 15;
    const int quad = lane >> 4;

    // stage 3-row, 66-px window of xT (zero-padded at borders)
    for (int idx = tid; idx < 1584; idx += 256) {
        const int pos = idx >> 3;
        const int part = idx & 7;
        const int r = pos / 66;
        const int xx = pos - r * 66;
        const int y = h + r - 1;
        const int xg = w0 + xx - 1;
        uint4 v = make_uint4(0u, 0u, 0u, 0u);
        if (y >= 0 && y < IH && xg >= 0 && xg < IW)
            v = *(const uint4*)(xT + (((size_t)b << 20) + (((y << 7) + xg) << 6) + (part << 3)));
        *(uint4*)&win[pos * 72 + part * 8] = v;
    }
    // stage weights k=0
    {
        const int o = tid >> 3;
        const int part = tid & 7;
        *(uint4*)&wks[0][o * 72 + part * 8] =
            *(const uint4*)(wt_om16 + (o << 6) + (part << 3));
    }
    __syncthreads();

    f32x4 acc[2] = {{0.f, 0.f, 0.f, 0.f}, {0.f, 0.f, 0.f, 0.f}};

    for (int k = 0; k < 9; ++k) {
        const int buf = k & 1;
        if (k < 8) {   // stage next weight slice into other buffer
            const int o = tid >> 3;
            const int part = tid & 7;
            *(uint4*)&wks[buf ^ 1][o * 72 + part * 8] =
                *(const uint4*)(wt_om16 + ((k + 1) << 11) + (o << 6) + (part << 3));
        }
        const int kh = k / 3;
        const int kw = k - kh * 3;
        const int posb = kh * 66 + wid * 16 + ln15 + kw;
        const unsigned short* wb = wks[buf];
#pragma unroll
        for (int ch = 0; ch < 2; ++ch) {
            const int c = (ch << 5) + (quad << 3);
            U4B8 a, b0, b1;
            a.u  = *(const uint4*)&win[posb * 72 + c];
            b0.u = *(const uint4*)&wb[ln15 * 72 + c];
            b1.u = *(const uint4*)&wb[(16 + ln15) * 72 + c];
            acc[0] = __builtin_amdgcn_mfma_f32_16x16x32_bf16(a.h, b0.h, acc[0], 0, 0, 0);
            acc[1] = __builtin_amdgcn_mfma_f32_16x16x32_bf16(a.h, b1.h, acc[1], 0, 0, 0);
        }
        __syncthreads();
    }

    // C/D layout: col(o)=lane&15, row(px)=quad*4+reg
    const int px0 = wid * 16 + quad * 4;
#pragma unroll
    for (int ot = 0; ot < 2; ++ot) {
        const int o = (ot << 4) + ln15;
        if (o >= 27) continue;
        const float bias = b_om[o];
        float4 r;
        r.x = acc[ot][0] + bias;
        r.y = acc[ot][1] + bias;
        r.z = acc[ot][2] + bias;
        r.w = acc[ot][3] + bias;
        if (o >= 18) {
            r.x = 2.0f / (1.0f + __expf(-r.x));
            r.y = 2.0f / (1.0f + __expf(-r.y));
            r.z = 2.0f / (1.0f + __expf(-r.z));
            r.w = 2.0f / (1.0f + __expf(-r.w));
        }
        *(float4*)&offm[(((size_t)(b * 27 + o)) << 14) + (h << 7) + w0 + px0] = r;
    }
}

// ---------------------------------------------------------------------------
// gather issue phase: compute corner weights (msk premultiplied) and ISSUE
// the 8 corner loads into registers. Consumed one tap later.
// offs is LDS, stride OFFS_STRIDE floats per channel.
// ---------------------------------------------------------------------------
__device__ __forceinline__ void issue_gather(
        const unsigned short* __restrict__ xb, const float* offs,
        int k, int lpx, int h, int quad, uint4* g, float* cw) {
    const float offy = offs[(k << 1) * OFFS_STRIDE + lpx];
    const float offx = offs[((k << 1) + 1) * OFFS_STRIDE + lpx];
    const float msk  = offs[(18 + k) * OFFS_STRIDE + lpx];
    const int kh = k / 3;
    const int kw = k - kh * 3;
    const float py  = (float)(h + kh - 1) + offy;
    const float pxf = (float)(lpx + kw - 1) + offx;
    const float y0f = floorf(py);
    const float x0f = floorf(pxf);
    const float fy = py - y0f;
    const float fx = pxf - x0f;
    const float wy0 = 1.0f - fy, wx0 = 1.0f - fx;
    const float vy0 = (y0f >= 0.0f && y0f <= 127.0f) ? 1.0f : 0.0f;
    const float vy1 = (y0f >= -1.0f && y0f <= 126.0f) ? 1.0f : 0.0f;
    const float vx0 = (x0f >= 0.0f && x0f <= 127.0f) ? 1.0f : 0.0f;
    const float vx1 = (x0f >= -1.0f && x0f <= 126.0f) ? 1.0f : 0.0f;
    cw[0] = wy0 * wx0 * vy0 * vx0 * msk;
    cw[1] = wy0 * fx  * vy0 * vx1 * msk;
    cw[2] = fy  * wx0 * vy1 * vx0 * msk;
    cw[3] = fy  * fx  * vy1 * vx1 * msk;
    const int y0i = min(max((int)y0f, 0), 127);
    const int y1i = min(max((int)y0f + 1, 0), 127);
    const int x0i = min(max((int)x0f, 0), 127);
    const int x1i = min(max((int)x0f + 1, 0), 127);
    const int cofs = quad << 3;
    const unsigned short* p00 = xb + ((((size_t)((y0i << 7) + x0i)) << 6) + cofs);
    const unsigned short* p01 = xb + ((((size_t)((y0i << 7) + x1i)) << 6) + cofs);
    const unsigned short* p10 = xb + ((((size_t)((y1i << 7) + x0i)) << 6) + cofs);
    const unsigned short* p11 = xb + ((((size_t)((y1i << 7) + x1i)) << 6) + cofs);
    g[0] = *(const uint4*)p00;  g[1] = *(const uint4*)(p00 + 32);
    g[2] = *(const uint4*)p01;  g[3] = *(const uint4*)(p01 + 32);
    g[4] = *(const uint4*)p10;  g[5] = *(const uint4*)(p10 + 32);
    g[6] = *(const uint4*)p11;  g[7] = *(const uint4*)(p11 + 32);
}

// ---------------------------------------------------------------------------
// consume phase: combine 8 corner vectors with 4 (msk-premul) weights via
// packed-f32 FMA, pack to bf16 A-fragments via hw cvt_pk.
// ---------------------------------------------------------------------------
__device__ __forceinline__ void pack_frags(const uint4* g, const float* cw,
                                           U4B8& a0, U4B8& a1) {
    f32x2 v2[8];
#pragma unroll
    for (int i = 0; i < 8; ++i) v2[i] = (f32x2){0.f, 0.f};
#pragma unroll
    for (int c = 0; c < 4; ++c) {
        f32x2 w2;
        w2.x = cw[c];
        w2.y = cw[c];
        const uint4 ga = g[2 * c];
        const uint4 gb = g[2 * c + 1];
        const unsigned int u[8] = {ga.x, ga.y, ga.z, ga.w, gb.x, gb.y, gb.z, gb.w};
#pragma unroll
        for (int i = 0; i < 8; ++i) {
            f32x2 x2;
            x2.x = __uint_as_float(u[i] << 16);
            x2.y = __uint_as_float(u[i] & 0xffff0000u);
            asm("v_pk_fma_f32 %0, %1, %2, %0" : "+v"(v2[i]) : "v"(x2), "v"(w2));
        }
    }
    unsigned int pk[8];
#pragma unroll
    for (int i = 0; i < 8; ++i)
        asm("v_cvt_pk_bf16_f32 %0, %1, %2"
            : "=v"(pk[i]) : "v"(v2[i].x), "v"(v2[i].y));
    a0.u = make_uint4(pk[0], pk[1], pk[2], pk[3]);
    a1.u = make_uint4(pk[4], pk[5], pk[6], pk[7]);
}

// ---------------------------------------------------------------------------
// Kernel 2: deformable conv. Block = 128px (one full row) x 64o, 8 waves.
// Same per-tap structure as R4, but the weight staging (512 uint4/tap) and
// the 9 barriers now serve 2x the pixels -> per-px overhead halved.
// A-frags: register gather pipeline (issue k+1 before consuming k).
// B-frags: LDS weight dbuf (lgkmcnt — decoupled from gather vmcnt).
// Barrier = lgkmcnt(0) + raw s_barrier: gather loads stay in flight.
// XCD swizzle: 1024 blocks, 128/image -> one image per XCD.
// ---------------------------------------------------------------------------
__global__ __launch_bounds__(512) void deform_mfma(
        const unsigned short* __restrict__ xT,
        const float* __restrict__ b_dc,
        const float* __restrict__ offm,              // [B][27][H][W]
        const unsigned short* __restrict__ wt_dc16,  // [9][64][64] (k,o,c)
        float* __restrict__ out) {
    __shared__ __align__(16) float offs[27 * OFFS_STRIDE];   // [ch][px]
    __shared__ __align__(16) unsigned short wks[2][64 * 72]; // [buf][o][72]

    const int tid = threadIdx.x;
    const int bid = blockIdx.x;
    const int swz = ((bid & 7) << 7) + (bid >> 3);   // XCD-contiguous (1024)
    const int b = swz >> 7;
    const int h = swz & 127;
    const int wid = tid >> 6;            // 0..7
    const int lane = tid & 63;
    const int ln15 = lane & 15;
    const int quad = lane >> 4;
    const int lpx = (wid << 4) + ln15;   // 0..127: pixel this lane owns

    // stage offsets/masks for the row's 128 pixels
    for (int i = tid; i < 27 * 128; i += 512) {
        const int ch = i >> 7;
        const int px = i & 127;
        offs[ch * OFFS_STRIDE + px] =
            offm[(((size_t)(b * 27 + ch)) << 14) + (h << 7) + px];
    }
    // stage weights k=0 into wks[0]: exactly 512 uint4 slots, 1 per thread
    const int so = tid >> 3, sp = tid & 7;
    *(uint4*)&wks[0][so * 72 + sp * 8] =
        *(const uint4*)(wt_dc16 + (so << 6) + (sp << 3));
    __syncthreads();

    const unsigned short* xb = xT + ((size_t)b << 20);

    f32x4 acc[4];
#pragma unroll
    for (int i = 0; i < 4; ++i) acc[i] = (f32x4){0.f, 0.f, 0.f, 0.f};

    uint4 g[2][8];
    float cw[2][4];
    issue_gather(xb, offs, 0, lpx, h, quad, g[0], cw[0]);

#pragma unroll
    for (int k = 0; k < 9; ++k) {
        const int cur = k & 1;
        const int nxt = cur ^ 1;
        if (k < 8) {
            // 1) weight load for k+1 (oldest in this iter's vmem FIFO)
            const uint4 wv = *(const uint4*)(wt_dc16 + ((k + 1) << 12) + (so << 6) + (sp << 3));
            // 2) issue next-tap gather loads (newest — stay in flight)
            issue_gather(xb, offs, k + 1, lpx, h, quad, g[nxt], cw[nxt]);
            // 3) ds_write W: waits vmcnt(8) -> drains W + gather(k) only
            *(uint4*)&wks[nxt][so * 72 + sp * 8] = wv;
        }
        // 4) pack tap k from last iteration's registers
        U4B8 a0, a1;
        pack_frags(g[cur], cw[cur], a0, a1);
        // 5) MFMA from LDS weight broadcast
        const unsigned short* wb = wks[cur];
#pragma unroll
        for (int ot = 0; ot < 4; ++ot) {
            U4B8 b0, b1;
            const unsigned short* base = &wb[((ot << 4) + ln15) * 72 + (quad << 3)];
            b0.u = *(const uint4*)base;
            b1.u = *(const uint4*)(base + 32);
            acc[ot] = __builtin_amdgcn_mfma_f32_16x16x32_bf16(a0.h, b0.h, acc[ot], 0, 0, 0);
            acc[ot] = __builtin_amdgcn_mfma_f32_16x16x32_bf16(a1.h, b1.h, acc[ot], 0, 0, 0);
        }
        // 6) dbuf barrier: LDS-only wait — gather(k+1) loads stay in flight
        if (k < 8) {
            asm volatile("s_waitcnt lgkmcnt(0)" ::: "memory");
            __builtin_amdgcn_s_barrier();
            __builtin_amdgcn_sched_barrier(0);
        }
    }

    // epilogue: col(o)=lane&15, row(px)=quad*4+reg
#pragma unroll
    for (int ot = 0; ot < 4; ++ot) {
        const int o = (ot << 4) + ln15;
        const float bias = b_dc[o];
        float4 r;
        r.x = acc[ot][0] + bias;
        r.y = acc[ot][1] + bias;
        r.z = acc[ot][2] + bias;
        r.w = acc[ot][3] + bias;
        *(float4*)&out[(((size_t)(b * 64 + o)) << 14) + (h << 7) + (wid << 4) + (quad << 2)] = r;
    }
}

extern "C" void kernel_launch(void* const* d_in, const int* in_sizes, int n_in,
                              void* d_out, int out_size, void* d_ws, size_t ws_size,
                              hipStream_t stream) {
    const float* x    = (const float*)d_in[0];
    const float* w_om = (const float*)d_in[1];
    const float* b_om = (const float*)d_in[2];
    const float* w_dc = (const float*)d_in[3];
    const float* b_dc = (const float*)d_in[4];
    float* out = (float*)d_out;
    float* ws  = (float*)d_ws;

    float* offm = ws + OFFM_OFF;
    unsigned short* xT      = (unsigned short*)(ws + XT_OFF);
    unsigned short* wt_dc16 = (unsigned short*)(ws + WTDC_OFF);
    unsigned short* wt_om16 = (unsigned short*)(ws + WTOM_OFF);

    transpose_weights<<<144, 256, 0, stream>>>(w_dc, w_om, wt_dc16, wt_om16);
    transpose_x<<<NB * IH, 256, 0, stream>>>(x, xT);
    conv_om_mfma<<<NB * IH * 2, 256, 0, stream>>>(xT, b_om, wt_om16, offm);
    deform_mfma<<<NB * IH, 512, 0, stream>>>(xT, b_dc, offm, wt_dc16, out);
}